// Round 11
// baseline (455.519 us; speedup 1.0000x reference)
//
#include <hip/hip_runtime.h>

typedef unsigned short ushort_t;
typedef unsigned int uint_t;
typedef __attribute__((ext_vector_type(8))) short bf8_t;   // 8 x bf16 (4 VGPRs)
typedef __attribute__((ext_vector_type(4))) float f4_t;    // MFMA acc
typedef __attribute__((ext_vector_type(4))) unsigned int u4_t;

#define NPTS 200000
#define MSUB 50000
#define KNBR 32
#define PK 15
#define INDIM 128
#define OUTDIM 256
#define HID 64
#define QD2 1024  // padded PK*HID (p=15 row zero)
#define NB1 1563  // conv1 blocks = ceil(NPTS/128)
#define NBT 1563  // convT blocks = ceil(MSUB/32)

__device__ __forceinline__ ushort_t f2bf(float f) {
  uint_t u = __float_as_uint(f);
  u = (u + 0x7fffu + ((u >> 16) & 1u)) >> 16;  // RNE
  return (ushort_t)u;
}
__device__ __forceinline__ float bf2f(ushort_t h) {
  return __uint_as_float(((uint_t)h) << 16);
}
__device__ __forceinline__ float lrelu(float x) { return fmaxf(x, 0.1f * x); }
__device__ __forceinline__ f4_t zero4() { f4_t z = {0.f, 0.f, 0.f, 0.f}; return z; }

// ---------------- prep: weight transposes to bf16 ----------------
__global__ void prep_w_kernel(const float* __restrict__ W1, const float* __restrict__ W2,
                              const float* __restrict__ Ws, const float* __restrict__ kpw,
                              ushort_t* __restrict__ W1t, ushort_t* __restrict__ W2t,
                              ushort_t* __restrict__ Wst, ushort_t* __restrict__ kpwT2) {
  const int base = blockIdx.x * blockDim.x + threadIdx.x;
  const int stride = gridDim.x * blockDim.x;
  for (int t = base; t < HID * INDIM; t += stride) {      // W1t[c][k] = W1[k][c]
    int c = t & 63, k = t >> 6;
    W1t[c * INDIM + k] = f2bf(W1[k * HID + c]);
  }
  for (int t = base; t < OUTDIM * HID; t += stride) {     // W2t[c][k]
    int c = t & 255, k = t >> 8;
    W2t[c * HID + k] = f2bf(W2[k * OUTDIM + c]);
  }
  for (int t = base; t < OUTDIM * INDIM; t += stride) {   // Wst[c][k]
    int c = t & 255, k = t >> 8;
    Wst[c * INDIM + k] = f2bf(Ws[k * OUTDIM + c]);
  }
  // kpwT2[d][s]: s-permuted to match gather's agg D-layout pack.
  // s = ((rr*2+nh)*64 + g*16 + r16)*2 + nl ; p = g*4+rr ; c = r16+(nh*2+nl)*16
  for (int t = base; t < HID * QD2; t += stride) {
    int d = t >> 10, s = t & 1023;
    int nl = s & 1, r16v = (s >> 1) & 15, gv = (s >> 5) & 3, nh = (s >> 7) & 1, rr = (s >> 8) & 3;
    int p = gv * 4 + rr, c = r16v + (nh * 2 + nl) * 16;
    float v = (p < PK) ? kpw[((long)p * HID + c) * HID + d] : 0.f;
    kpwT2[d * QD2 + s] = f2bf(v);
  }
}

// ---------------- conv1: feat f32 -> feat16 + x1raw [N,64] + col-major partials ----------
__global__ __launch_bounds__(256) void conv1_kernel(const float* __restrict__ feat,
                                                    const ushort_t* __restrict__ W1t,
                                                    ushort_t* __restrict__ feat16,
                                                    ushort_t* __restrict__ x1,
                                                    float* __restrict__ part1) {
  const int tid = threadIdx.x, wid = tid >> 6, lane = tid & 63;
  const int g = lane >> 4, r16 = lane & 15;
  const int rowbase = blockIdx.x * 128 + wid * 32;
  f4_t acc[2][4];
#pragma unroll
  for (int mi = 0; mi < 2; ++mi)
#pragma unroll
    for (int ni = 0; ni < 4; ++ni) acc[mi][ni] = zero4();
#pragma unroll
  for (int kc = 0; kc < 4; ++kc) {
    const int k0 = kc * 32 + g * 8;
    bf8_t a[2], b[4];
#pragma unroll
    for (int mi = 0; mi < 2; ++mi) {
      const int row = rowbase + mi * 16 + r16;
      const int rowc = (row < NPTS) ? row : 0;
      const float4 f0 = *(const float4*)(feat + (long)rowc * INDIM + k0);
      const float4 f1 = *(const float4*)(feat + (long)rowc * INDIM + k0 + 4);
      a[mi][0] = (short)f2bf(f0.x); a[mi][1] = (short)f2bf(f0.y);
      a[mi][2] = (short)f2bf(f0.z); a[mi][3] = (short)f2bf(f0.w);
      a[mi][4] = (short)f2bf(f1.x); a[mi][5] = (short)f2bf(f1.y);
      a[mi][6] = (short)f2bf(f1.z); a[mi][7] = (short)f2bf(f1.w);
      if (row < NPTS) *(bf8_t*)(feat16 + (long)row * INDIM + k0) = a[mi];
    }
#pragma unroll
    for (int ni = 0; ni < 4; ++ni)
      b[ni] = *(const bf8_t*)(W1t + (r16 + ni * 16) * INDIM + k0);
#pragma unroll
    for (int mi = 0; mi < 2; ++mi)
#pragma unroll
      for (int ni = 0; ni < 4; ++ni)
        acc[mi][ni] = __builtin_amdgcn_mfma_f32_16x16x32_bf16(a[mi], b[ni], acc[mi][ni], 0, 0, 0);
  }
  __shared__ float red[2][64];
  if (tid < 64) { red[0][tid] = 0.f; red[1][tid] = 0.f; }
  __syncthreads();
  float cs[4] = {0.f, 0.f, 0.f, 0.f}, cq[4] = {0.f, 0.f, 0.f, 0.f};
#pragma unroll
  for (int mi = 0; mi < 2; ++mi)
#pragma unroll
    for (int rr = 0; rr < 4; ++rr) {
      const int row = rowbase + mi * 16 + g * 4 + rr;
      if (row < NPTS) {
#pragma unroll
        for (int ni = 0; ni < 4; ++ni) {
          const float v = acc[mi][ni][rr];
          cs[ni] += v;
          cq[ni] += v * v;
          x1[(long)row * HID + r16 + ni * 16] = f2bf(v);
        }
      }
    }
#pragma unroll
  for (int ni = 0; ni < 4; ++ni) {
    atomicAdd(&red[0][r16 + ni * 16], cs[ni]);
    atomicAdd(&red[1][r16 + ni * 16], cq[ni]);
  }
  __syncthreads();
  if (tid < 128) {
    const float v = (tid < 64) ? red[0][tid] : red[1][tid - 64];
    part1[(long)tid * NB1 + blockIdx.x] = v;  // column-major partials
  }
}

// ---------------- reduce conv1 partials + BN1 affine (64 blocks) ----------------
__global__ __launch_bounds__(256) void reduce1fin_kernel(const float* __restrict__ part1,
                                                         const float* __restrict__ g1,
                                                         const float* __restrict__ be1,
                                                         float* __restrict__ st) {
  const int c = blockIdx.x, tid = threadIdx.x;
  const int slot = (tid < 128) ? c : (64 + c);
  const float* src = part1 + (long)slot * NB1;
  float acc = 0.f;
  for (int i = tid & 127; i < NB1; i += 128) acc += src[i];
  __shared__ float sm[256];
  sm[tid] = acc;
  __syncthreads();
  for (int s = 64; s > 0; s >>= 1) {
    if ((tid & 127) < s) sm[tid] += sm[tid + s];
    __syncthreads();
  }
  if (tid == 0) {
    const float mu = sm[0] / (float)NPTS;
    const float var = sm[128] / (float)NPTS - mu * mu;
    const float a = g1[c] * rsqrtf(var + 1e-5f);
    st[c] = a;
    st[64 + c] = be1[c] - mu * a;
  }
}

// ---------------- gkp: gather + per-m agg MFMA + fused [16x1024]@[1024x64] GEMM ----------
// 512 threads = 8 waves, 16 m per block (2 per wave). x1 staged in 16-row CHUNKS:
// ft2 = [8][32][20] u32 (20 KB) + aggT 32 KB = 53248 B -> 3 blocks/CU (24 waves, 75%).
// Chunked MFMA: K=32 mfma with A zeroed for k>=16 (junk B contributes 0); acc carries.
__global__ __launch_bounds__(512, 6) void gkp_kernel(
    const float* __restrict__ points, const float* __restrict__ subp,
    const int* __restrict__ pools, const float* __restrict__ kp,
    const ushort_t* __restrict__ x1, const ushort_t* __restrict__ feat16,
    const float* __restrict__ st, const ushort_t* __restrict__ kpwT2,
    ushort_t* __restrict__ x2, ushort_t* __restrict__ scmax) {
  const int tid = threadIdx.x, wid = tid >> 6, lane = tid & 63;
  const int g = lane >> 4, r16 = lane & 15, l31 = lane & 31, hi = lane >> 5;
  const int mbase = blockIdx.x * 16;
  __shared__ __align__(16) char aggT[16 * 2048];   // 16 rows x 1024 bf16, XOR-swizzled (32 KB)
  __shared__ __align__(16) uint_t ft2[8][32][20];  // per-wave 16-row chunk (20 KB)
  // per-lane BN1 affine for c = r16 + ni*16
  float A4[4], S4[4];
#pragma unroll
  for (int ni = 0; ni < 4; ++ni) {
    A4[ni] = st[r16 + ni * 16];
    S4[ni] = st[64 + r16 + ni * 16];
  }
  const int p = r16;
  const int pc = (p < PK) ? p : 0;
  const float kx = kp[pc * 3 + 0], ky = kp[pc * 3 + 1], kz = kp[pc * 3 + 2];
  const int gc = g & 1;

#pragma unroll
  for (int mm = 0; mm < 2; ++mm) {
    const int lm = wid * 2 + mm;
    const int m = mbase + lm;
    // neighbor idx + point coords in lanes 0..31 (broadcast via shfl)
    const int idx0 = pools[m * KNBR + l31];
    float px = 0.f, py = 0.f, pz = 0.f;
    if (lane < 32) {
      px = points[idx0 * 3 + 0];
      py = points[idx0 * 3 + 1];
      pz = points[idx0 * 3 + 2];
    }
    const float sx = subp[m * 3 + 0], sy = subp[m * 3 + 1], sz = subp[m * 3 + 2];
    const float kxx = kx + sx, kyy = ky + sy, kzz = kz + sz;
    f4_t acc[4];
#pragma unroll
    for (int ni = 0; ni < 4; ++ni) acc[ni] = zero4();
    // two 16-neighbor chunks; wave-local buffer reuse (compiler orders via lgkmcnt)
#pragma unroll
    for (int t = 0; t < 2; ++t) {
      // stage 16 rows of x1 -> ft2[c2][k], k = 0..15
#pragma unroll
      for (int i = 0; i < 8; ++i) {
        const int k = 2 * i + hi;
        const int n = __shfl(idx0, t * 16 + k);
        ft2[wid][l31][k] = *(const uint_t*)(x1 + (long)n * HID + l31 * 2);
      }
      // A fragment: w for k = gc*8+j of this chunk; zero for g>=2 (and p>=PK)
      bf8_t afrag;
#pragma unroll
      for (int j = 0; j < 8; ++j) {
        const int kk = t * 16 + gc * 8 + j;
        const float dx = __shfl(px, kk) - kxx;
        const float dy = __shfl(py, kk) - kyy;
        const float dz = __shfl(pz, kk) - kzz;
        const float dist = sqrtf(dx * dx + dy * dy + dz * dz);
        float w = fmaxf(0.f, 1.f - dist * 20.f);
        if (p >= PK || g >= 2) w = 0.f;
        afrag[j] = (short)f2bf(w);
      }
      // B fragments: extract + BN1 + lrelu + pack from ft2[c2][gc*8 .. gc*8+7]
#pragma unroll
      for (int ni = 0; ni < 4; ++ni) {
        const int c = r16 + ni * 16;
        const int c2 = c >> 1;
        const int sh = (c & 1) * 16;
        const float A = A4[ni], S = S4[ni];
        const uint_t* src = &ft2[wid][c2][gc * 8];
        const u4_t v0 = *(const u4_t*)src;        // 80B row stride -> 16B aligned
        const u4_t v1 = *(const u4_t*)(src + 4);
        bf8_t bfrag;
#pragma unroll
        for (int j = 0; j < 4; ++j) {
          const float xa = __uint_as_float(((v0[j] >> sh) & 0xffffu) << 16);
          bfrag[j] = (short)f2bf(lrelu(A * xa + S));
          const float xb = __uint_as_float(((v1[j] >> sh) & 0xffffu) << 16);
          bfrag[4 + j] = (short)f2bf(lrelu(A * xb + S));
        }
        acc[ni] = __builtin_amdgcn_mfma_f32_16x16x32_bf16(afrag, bfrag, acc[ni], 0, 0, 0);
      }
    }
    // store agg row into swizzled LDS: s32 = (rr*2+nh)*64 + g*16 + r16
    char* rowp = aggT + lm * 2048;
#pragma unroll
    for (int rr = 0; rr < 4; ++rr)
#pragma unroll
      for (int nh = 0; nh < 2; ++nh) {
        const uint_t v =
            (uint_t)f2bf(acc[nh * 2][rr]) | ((uint_t)f2bf(acc[nh * 2 + 1][rr]) << 16);
        int byte = ((rr * 2 + nh) * 64 + g * 16 + r16) * 4;
        byte ^= (lm & 7) << 4;
        *(uint_t*)(rowp + byte) = v;
      }
    // shortcut: max over neighbors (packed u32, full row per instruction)
    float mx0 = -3.0e38f, mx1 = -3.0e38f;
#pragma unroll
    for (int k = 0; k < KNBR; ++k) {
      const int n = __shfl(idx0, k);
      const uint_t v = *(const uint_t*)(feat16 + (long)n * INDIM + lane * 2);
      mx0 = fmaxf(mx0, __uint_as_float(v << 16));
      mx1 = fmaxf(mx1, __uint_as_float(v & 0xffff0000u));
    }
    ((uint_t*)scmax)[(long)m * 64 + lane] =
        (uint_t)(__float_as_uint(mx0) >> 16) | (__float_as_uint(mx1) & 0xffff0000u);
  }
  __syncthreads();
  // phase 2: x2[16 m x 64 d] = aggT[16 x 1024] @ kpwT2^T ; waves 0..3, 16 d-cols each
  if (wid < 4) {
    f4_t acc2 = zero4();
    const ushort_t* brow = kpwT2 + (long)(wid * 16 + r16) * QD2;
#pragma unroll 8
    for (int kc = 0; kc < 32; ++kc) {
      int byte = (kc * 64 + g * 16) ^ ((r16 & 7) << 4);
      const bf8_t a = *(const bf8_t*)(aggT + r16 * 2048 + byte);
      const bf8_t b = *(const bf8_t*)(brow + kc * 32 + g * 8);
      acc2 = __builtin_amdgcn_mfma_f32_16x16x32_bf16(a, b, acc2, 0, 0, 0);
    }
#pragma unroll
    for (int rr = 0; rr < 4; ++rr) {
      const int m = mbase + g * 4 + rr;
      x2[(long)m * HID + wid * 16 + r16] = f2bf(lrelu(acc2[rr]));
    }
  }
}

// ---------------- conv2 + shortcut conv merged: [M,KD] @ [KD,256] + col-major partials ----
template <int KD>
__device__ __forceinline__ void convT_body(const ushort_t* __restrict__ A,
                                           const ushort_t* __restrict__ Bt,
                                           ushort_t* __restrict__ Oraw,
                                           float* __restrict__ part, int blk) {
  const int tid = threadIdx.x, lane = tid & 63;
  const int wid = tid >> 6;
  const int g = lane >> 4, r16 = lane & 15;
  const int rowbase = blk * 32;
  const int colbase = wid * 64;
  f4_t acc[2][4];
#pragma unroll
  for (int mi = 0; mi < 2; ++mi)
#pragma unroll
    for (int ni = 0; ni < 4; ++ni) acc[mi][ni] = zero4();
#pragma unroll
  for (int kc = 0; kc < KD / 32; ++kc) {
    const int k0 = kc * 32 + g * 8;
    bf8_t a[2], b[4];
#pragma unroll
    for (int mi = 0; mi < 2; ++mi) {
      int row = rowbase + mi * 16 + r16;
      if (row >= MSUB) row = 0;
      a[mi] = *(const bf8_t*)(A + (long)row * KD + k0);
    }
#pragma unroll
    for (int ni = 0; ni < 4; ++ni)
      b[ni] = *(const bf8_t*)(Bt + (long)(colbase + r16 + ni * 16) * KD + k0);
#pragma unroll
    for (int mi = 0; mi < 2; ++mi)
#pragma unroll
      for (int ni = 0; ni < 4; ++ni)
        acc[mi][ni] = __builtin_amdgcn_mfma_f32_16x16x32_bf16(a[mi], b[ni], acc[mi][ni], 0, 0, 0);
  }
  __shared__ float red[2][256];
  red[0][tid] = 0.f;
  red[1][tid] = 0.f;
  __syncthreads();
  float cs[4] = {0.f, 0.f, 0.f, 0.f}, cq[4] = {0.f, 0.f, 0.f, 0.f};
#pragma unroll
  for (int mi = 0; mi < 2; ++mi)
#pragma unroll
    for (int rr = 0; rr < 4; ++rr) {
      const int row = rowbase + mi * 16 + g * 4 + rr;
      if (row < MSUB) {
#pragma unroll
        for (int ni = 0; ni < 4; ++ni) {
          const float v = acc[mi][ni][rr];
          cs[ni] += v;
          cq[ni] += v * v;
          Oraw[(long)row * OUTDIM + colbase + r16 + ni * 16] = f2bf(v);
        }
      }
    }
#pragma unroll
  for (int ni = 0; ni < 4; ++ni) {
    atomicAdd(&red[0][colbase + r16 + ni * 16], cs[ni]);
    atomicAdd(&red[1][colbase + r16 + ni * 16], cq[ni]);
  }
  __syncthreads();
  part[(long)tid * NBT + blk] = red[0][tid];          // column-major
  part[(long)(256 + tid) * NBT + blk] = red[1][tid];
}

__global__ __launch_bounds__(256) void convT_merged_kernel(
    const ushort_t* __restrict__ x2, const ushort_t* __restrict__ W2t,
    const ushort_t* __restrict__ scmax, const ushort_t* __restrict__ Wst,
    ushort_t* __restrict__ x3, ushort_t* __restrict__ scraw,
    float* __restrict__ part2, float* __restrict__ part3) {
  const int b = blockIdx.x;
  if (b < NBT)
    convT_body<HID>(x2, W2t, x3, part2, b);
  else
    convT_body<INDIM>(scmax, Wst, scraw, part3, b - NBT);
}

// ---------------- reduce convT partials + BN2/BN3 affines (512 blocks) ----------------
__global__ __launch_bounds__(256) void reduce23fin_kernel(const float* __restrict__ part2,
                                                          const float* __restrict__ part3,
                                                          const float* __restrict__ g2,
                                                          const float* __restrict__ be2,
                                                          const float* __restrict__ gs,
                                                          const float* __restrict__ bes,
                                                          float* __restrict__ st) {
  const int blk = blockIdx.x, tid = threadIdx.x;
  const int sc = blk >> 8, c = blk & 255;
  const float* part = sc ? part3 : part2;
  const int slot = (tid < 128) ? c : (256 + c);
  const float* src = part + (long)slot * NBT;
  float acc = 0.f;
  for (int i = tid & 127; i < NBT; i += 128) acc += src[i];
  __shared__ float sm[256];
  sm[tid] = acc;
  __syncthreads();
  for (int s = 64; s > 0; s >>= 1) {
    if ((tid & 127) < s) sm[tid] += sm[tid + s];
    __syncthreads();
  }
  if (tid == 0) {
    const float mu = sm[0] / (float)MSUB;
    const float var = sm[128] / (float)MSUB - mu * mu;
    const float a = (sc ? gs : g2)[c] * rsqrtf(var + 1e-5f);
    const int off = sc ? 640 : 128;
    st[off + c] = a;
    st[off + 256 + c] = (sc ? bes : be2)[c] - mu * a;
  }
}

// ---------------- final: BN2/BN3 + lrelu + add + lrelu ----------------
__global__ __launch_bounds__(256) void final_kernel(const ushort_t* __restrict__ x3,
                                                    const ushort_t* __restrict__ sc,
                                                    const float* __restrict__ st,
                                                    float* __restrict__ out) {
  const int i = blockIdx.x * 256 + threadIdx.x;  // 4 elems per thread
  const int c0 = (i * 4) & 255;
  const uint2 xv = ((const uint2*)x3)[i];
  const uint2 sv = ((const uint2*)sc)[i];
  float xs[4] = {bf2f((ushort_t)(xv.x & 0xffffu)), bf2f((ushort_t)(xv.x >> 16)),
                 bf2f((ushort_t)(xv.y & 0xffffu)), bf2f((ushort_t)(xv.y >> 16))};
  float ss[4] = {bf2f((ushort_t)(sv.x & 0xffffu)), bf2f((ushort_t)(sv.x >> 16)),
                 bf2f((ushort_t)(sv.y & 0xffffu)), bf2f((ushort_t)(sv.y >> 16))};
  float r[4];
#pragma unroll
  for (int j = 0; j < 4; ++j) {
    const int c = c0 + j;
    const float v = lrelu(st[128 + c] * xs[j] + st[384 + c]);
    const float u = lrelu(st[640 + c] * ss[j] + st[896 + c]);
    r[j] = lrelu(v + u);
  }
  ((float4*)out)[i] = make_float4(r[0], r[1], r[2], r[3]);
}

extern "C" void kernel_launch(void* const* d_in, const int* in_sizes, int n_in,
                              void* d_out, int out_size, void* d_ws, size_t ws_size,
                              hipStream_t stream) {
  (void)in_sizes; (void)n_in; (void)out_size;
  const float* points = (const float*)d_in[0];
  const float* subp = (const float*)d_in[1];
  const float* feat = (const float*)d_in[2];
  const int* pools = (const int*)d_in[3];
  const float* kp = (const float*)d_in[4];
  const float* W1 = (const float*)d_in[5];
  const float* g1 = (const float*)d_in[7];
  const float* be1 = (const float*)d_in[8];
  const float* kpw = (const float*)d_in[9];
  const float* W2 = (const float*)d_in[10];
  const float* g2 = (const float*)d_in[12];
  const float* be2 = (const float*)d_in[13];
  const float* Wsm = (const float*)d_in[14];
  const float* gs = (const float*)d_in[16];
  const float* bes = (const float*)d_in[17];
  float* out = (float*)d_out;

  char* w = (char*)d_ws;
  size_t o = 0;
  ushort_t* feat16 = (ushort_t*)(w + o); o += (size_t)NPTS * INDIM * 2;   // 51.2 MB
  ushort_t* x1 = (ushort_t*)(w + o);     o += (size_t)NPTS * HID * 2;     // 25.6 MB
  ushort_t* x2 = (ushort_t*)(w + o);     o += (size_t)MSUB * HID * 2;     // 6.4 MB
  ushort_t* x3 = (ushort_t*)(w + o);     o += (size_t)MSUB * OUTDIM * 2;  // 25.6 MB
  ushort_t* scmax = (ushort_t*)(w + o);  o += (size_t)MSUB * INDIM * 2;   // 12.8 MB
  ushort_t* scraw = (ushort_t*)(w + o);  o += (size_t)MSUB * OUTDIM * 2;  // 25.6 MB
  float* part1 = (float*)(w + o);        o += (size_t)128 * NB1 * 4;      // 0.8 MB
  float* part2 = (float*)(w + o);        o += (size_t)512 * NBT * 4;      // 3.2 MB
  float* part3 = (float*)(w + o);        o += (size_t)512 * NBT * 4;      // 3.2 MB
  ushort_t* W1t = (ushort_t*)(w + o);    o += HID * INDIM * 2;
  ushort_t* W2t = (ushort_t*)(w + o);    o += OUTDIM * HID * 2;
  ushort_t* Wst = (ushort_t*)(w + o);    o += OUTDIM * INDIM * 2;
  ushort_t* kpwT2 = (ushort_t*)(w + o);  o += HID * QD2 * 2;
  float* st = (float*)(w + o);           o += 1152 * 4;
  if (ws_size < o) return;  // fail cleanly

  prep_w_kernel<<<64, 256, 0, stream>>>(W1, W2, Wsm, kpw, W1t, W2t, Wst, kpwT2);
  conv1_kernel<<<NB1, 256, 0, stream>>>(feat, W1t, feat16, x1, part1);
  reduce1fin_kernel<<<64, 256, 0, stream>>>(part1, g1, be1, st);
  gkp_kernel<<<MSUB / 16, 512, 0, stream>>>(points, subp, pools, kp, x1, feat16, st,
                                            kpwT2, x2, scmax);
  convT_merged_kernel<<<2 * NBT, 256, 0, stream>>>(x2, W2t, scmax, Wst, x3, scraw,
                                                   part2, part3);
  reduce23fin_kernel<<<512, 256, 0, stream>>>(part2, part3, g2, be2, gs, bes, st);
  final_kernel<<<MSUB * OUTDIM / 1024, 256, 0, stream>>>(x3, scraw, st, out);
}

// Round 12
// 292.339 us; speedup vs baseline: 1.5582x; 1.5582x over previous
//
#include <hip/hip_runtime.h>

typedef unsigned short ushort_t;
typedef unsigned int uint_t;
typedef __attribute__((ext_vector_type(8))) short bf8_t;   // 8 x bf16 (4 VGPRs)
typedef __attribute__((ext_vector_type(4))) float f4_t;    // MFMA acc
typedef __attribute__((ext_vector_type(4))) unsigned int u4_t;

#define NPTS 200000
#define MSUB 50000
#define KNBR 32
#define PK 15
#define INDIM 128
#define OUTDIM 256
#define HID 64
#define QD2 1024  // padded PK*HID (p=15 row zero)
#define NB1 1563  // conv1 blocks = ceil(NPTS/128)
#define NBT 1563  // convT blocks = ceil(MSUB/32)

__device__ __forceinline__ ushort_t f2bf(float f) {
  uint_t u = __float_as_uint(f);
  u = (u + 0x7fffu + ((u >> 16) & 1u)) >> 16;  // RNE
  return (ushort_t)u;
}
__device__ __forceinline__ float bf2f(ushort_t h) {
  return __uint_as_float(((uint_t)h) << 16);
}
__device__ __forceinline__ float lrelu(float x) { return fmaxf(x, 0.1f * x); }
__device__ __forceinline__ f4_t zero4() { f4_t z = {0.f, 0.f, 0.f, 0.f}; return z; }

// ---------------- prep: weight transposes to bf16 ----------------
__global__ void prep_w_kernel(const float* __restrict__ W1, const float* __restrict__ W2,
                              const float* __restrict__ Ws, const float* __restrict__ kpw,
                              ushort_t* __restrict__ W1t, ushort_t* __restrict__ W2t,
                              ushort_t* __restrict__ Wst, ushort_t* __restrict__ kpwT2) {
  const int base = blockIdx.x * blockDim.x + threadIdx.x;
  const int stride = gridDim.x * blockDim.x;
  for (int t = base; t < HID * INDIM; t += stride) {      // W1t[c][k] = W1[k][c]
    int c = t & 63, k = t >> 6;
    W1t[c * INDIM + k] = f2bf(W1[k * HID + c]);
  }
  for (int t = base; t < OUTDIM * HID; t += stride) {     // W2t[c][k]
    int c = t & 255, k = t >> 8;
    W2t[c * HID + k] = f2bf(W2[k * OUTDIM + c]);
  }
  for (int t = base; t < OUTDIM * INDIM; t += stride) {   // Wst[c][k]
    int c = t & 255, k = t >> 8;
    Wst[c * INDIM + k] = f2bf(Ws[k * OUTDIM + c]);
  }
  // kpwT2[d][s]: s-permuted to match gather's agg D-layout pack.
  // s = ((rr*2+nh)*64 + g*16 + r16)*2 + nl ; p = g*4+rr ; c = r16+(nh*2+nl)*16
  for (int t = base; t < HID * QD2; t += stride) {
    int d = t >> 10, s = t & 1023;
    int nl = s & 1, r16v = (s >> 1) & 15, gv = (s >> 5) & 3, nh = (s >> 7) & 1, rr = (s >> 8) & 3;
    int p = gv * 4 + rr, c = r16v + (nh * 2 + nl) * 16;
    float v = (p < PK) ? kpw[((long)p * HID + c) * HID + d] : 0.f;
    kpwT2[d * QD2 + s] = f2bf(v);
  }
}

// ---------------- conv1: feat f32 -> feat16 + x1raw [N,64] + col-major partials ----------
__global__ __launch_bounds__(256) void conv1_kernel(const float* __restrict__ feat,
                                                    const ushort_t* __restrict__ W1t,
                                                    ushort_t* __restrict__ feat16,
                                                    ushort_t* __restrict__ x1,
                                                    float* __restrict__ part1) {
  const int tid = threadIdx.x, wid = tid >> 6, lane = tid & 63;
  const int g = lane >> 4, r16 = lane & 15;
  const int rowbase = blockIdx.x * 128 + wid * 32;
  f4_t acc[2][4];
#pragma unroll
  for (int mi = 0; mi < 2; ++mi)
#pragma unroll
    for (int ni = 0; ni < 4; ++ni) acc[mi][ni] = zero4();
#pragma unroll
  for (int kc = 0; kc < 4; ++kc) {
    const int k0 = kc * 32 + g * 8;
    bf8_t a[2], b[4];
#pragma unroll
    for (int mi = 0; mi < 2; ++mi) {
      const int row = rowbase + mi * 16 + r16;
      const int rowc = (row < NPTS) ? row : 0;
      const float4 f0 = *(const float4*)(feat + (long)rowc * INDIM + k0);
      const float4 f1 = *(const float4*)(feat + (long)rowc * INDIM + k0 + 4);
      a[mi][0] = (short)f2bf(f0.x); a[mi][1] = (short)f2bf(f0.y);
      a[mi][2] = (short)f2bf(f0.z); a[mi][3] = (short)f2bf(f0.w);
      a[mi][4] = (short)f2bf(f1.x); a[mi][5] = (short)f2bf(f1.y);
      a[mi][6] = (short)f2bf(f1.z); a[mi][7] = (short)f2bf(f1.w);
      if (row < NPTS) *(bf8_t*)(feat16 + (long)row * INDIM + k0) = a[mi];
    }
#pragma unroll
    for (int ni = 0; ni < 4; ++ni)
      b[ni] = *(const bf8_t*)(W1t + (r16 + ni * 16) * INDIM + k0);
#pragma unroll
    for (int mi = 0; mi < 2; ++mi)
#pragma unroll
      for (int ni = 0; ni < 4; ++ni)
        acc[mi][ni] = __builtin_amdgcn_mfma_f32_16x16x32_bf16(a[mi], b[ni], acc[mi][ni], 0, 0, 0);
  }
  __shared__ float red[2][64];
  if (tid < 64) { red[0][tid] = 0.f; red[1][tid] = 0.f; }
  __syncthreads();
  float cs[4] = {0.f, 0.f, 0.f, 0.f}, cq[4] = {0.f, 0.f, 0.f, 0.f};
#pragma unroll
  for (int mi = 0; mi < 2; ++mi)
#pragma unroll
    for (int rr = 0; rr < 4; ++rr) {
      const int row = rowbase + mi * 16 + g * 4 + rr;
      if (row < NPTS) {
#pragma unroll
        for (int ni = 0; ni < 4; ++ni) {
          const float v = acc[mi][ni][rr];
          cs[ni] += v;
          cq[ni] += v * v;
          x1[(long)row * HID + r16 + ni * 16] = f2bf(v);
        }
      }
    }
#pragma unroll
  for (int ni = 0; ni < 4; ++ni) {
    atomicAdd(&red[0][r16 + ni * 16], cs[ni]);
    atomicAdd(&red[1][r16 + ni * 16], cq[ni]);
  }
  __syncthreads();
  if (tid < 128) {
    const float v = (tid < 64) ? red[0][tid] : red[1][tid - 64];
    part1[(long)tid * NB1 + blockIdx.x] = v;  // column-major partials
  }
}

// ---------------- reduce conv1 partials + BN1 affine (64 blocks) ----------------
__global__ __launch_bounds__(256) void reduce1fin_kernel(const float* __restrict__ part1,
                                                         const float* __restrict__ g1,
                                                         const float* __restrict__ be1,
                                                         float* __restrict__ st) {
  const int c = blockIdx.x, tid = threadIdx.x;
  const int slot = (tid < 128) ? c : (64 + c);
  const float* src = part1 + (long)slot * NB1;
  float acc = 0.f;
  for (int i = tid & 127; i < NB1; i += 128) acc += src[i];
  __shared__ float sm[256];
  sm[tid] = acc;
  __syncthreads();
  for (int s = 64; s > 0; s >>= 1) {
    if ((tid & 127) < s) sm[tid] += sm[tid + s];
    __syncthreads();
  }
  if (tid == 0) {
    const float mu = sm[0] / (float)NPTS;
    const float var = sm[128] / (float)NPTS - mu * mu;
    const float a = g1[c] * rsqrtf(var + 1e-5f);
    st[c] = a;
    st[64 + c] = be1[c] - mu * a;
  }
}

// ---------------- gkp: gather + per-m agg MFMA + fused [16x1024]@[1024x64] GEMM ----------
// 512 threads = 8 waves, 16 m per block (2 per wave). x1 staged in 16-row CHUNKS:
// ft2 = [8][32][20] u32 (20 KB) + aggT 32 KB = 53248 B -> 3 blocks/CU if VGPR<=64.
// Launch bounds (512,4): R9-proven, VGPR=64, NO SPILLS (R11's (512,6) forced 40 -> spilled).
__global__ __launch_bounds__(512, 4) void gkp_kernel(
    const float* __restrict__ points, const float* __restrict__ subp,
    const int* __restrict__ pools, const float* __restrict__ kp,
    const ushort_t* __restrict__ x1, const ushort_t* __restrict__ feat16,
    const float* __restrict__ st, const ushort_t* __restrict__ kpwT2,
    ushort_t* __restrict__ x2, ushort_t* __restrict__ scmax) {
  const int tid = threadIdx.x, wid = tid >> 6, lane = tid & 63;
  const int g = lane >> 4, r16 = lane & 15, l31 = lane & 31, hi = lane >> 5;
  const int mbase = blockIdx.x * 16;
  __shared__ __align__(16) char aggT[16 * 2048];   // 16 rows x 1024 bf16, XOR-swizzled (32 KB)
  __shared__ __align__(16) uint_t ft2[8][32][20];  // per-wave 16-row chunk (20 KB)
  // per-lane BN1 affine for c = r16 + ni*16
  float A4[4], S4[4];
#pragma unroll
  for (int ni = 0; ni < 4; ++ni) {
    A4[ni] = st[r16 + ni * 16];
    S4[ni] = st[64 + r16 + ni * 16];
  }
  const int p = r16;
  const int pc = (p < PK) ? p : 0;
  const float kx = kp[pc * 3 + 0], ky = kp[pc * 3 + 1], kz = kp[pc * 3 + 2];
  const int gc = g & 1;

#pragma unroll
  for (int mm = 0; mm < 2; ++mm) {
    const int lm = wid * 2 + mm;
    const int m = mbase + lm;
    // neighbor idx + point coords in lanes 0..31 (broadcast via shfl)
    const int idx0 = pools[m * KNBR + l31];
    float px = 0.f, py = 0.f, pz = 0.f;
    if (lane < 32) {
      px = points[idx0 * 3 + 0];
      py = points[idx0 * 3 + 1];
      pz = points[idx0 * 3 + 2];
    }
    const float sx = subp[m * 3 + 0], sy = subp[m * 3 + 1], sz = subp[m * 3 + 2];
    const float kxx = kx + sx, kyy = ky + sy, kzz = kz + sz;
    f4_t acc[4];
#pragma unroll
    for (int ni = 0; ni < 4; ++ni) acc[ni] = zero4();
    // two 16-neighbor chunks; wave-local buffer reuse (compiler orders via lgkmcnt)
#pragma unroll
    for (int t = 0; t < 2; ++t) {
      // stage 16 rows of x1 -> ft2[c2][k], k = 0..15
#pragma unroll
      for (int i = 0; i < 8; ++i) {
        const int k = 2 * i + hi;
        const int n = __shfl(idx0, t * 16 + k);
        ft2[wid][l31][k] = *(const uint_t*)(x1 + (long)n * HID + l31 * 2);
      }
      // A fragment: w for k = gc*8+j of this chunk; zero for g>=2 (and p>=PK)
      bf8_t afrag;
#pragma unroll
      for (int j = 0; j < 8; ++j) {
        const int kk = t * 16 + gc * 8 + j;
        const float dx = __shfl(px, kk) - kxx;
        const float dy = __shfl(py, kk) - kyy;
        const float dz = __shfl(pz, kk) - kzz;
        const float dist = sqrtf(dx * dx + dy * dy + dz * dz);
        float w = fmaxf(0.f, 1.f - dist * 20.f);
        if (p >= PK || g >= 2) w = 0.f;
        afrag[j] = (short)f2bf(w);
      }
      // B fragments: extract + BN1 + lrelu + pack from ft2[c2][gc*8 .. gc*8+7]
#pragma unroll
      for (int ni = 0; ni < 4; ++ni) {
        const int c = r16 + ni * 16;
        const int c2 = c >> 1;
        const int sh = (c & 1) * 16;
        const float A = A4[ni], S = S4[ni];
        const uint_t* src = &ft2[wid][c2][gc * 8];
        const u4_t v0 = *(const u4_t*)src;        // 80B row stride -> 16B aligned
        const u4_t v1 = *(const u4_t*)(src + 4);
        bf8_t bfrag;
#pragma unroll
        for (int j = 0; j < 4; ++j) {
          const float xa = __uint_as_float(((v0[j] >> sh) & 0xffffu) << 16);
          bfrag[j] = (short)f2bf(lrelu(A * xa + S));
          const float xb = __uint_as_float(((v1[j] >> sh) & 0xffffu) << 16);
          bfrag[4 + j] = (short)f2bf(lrelu(A * xb + S));
        }
        acc[ni] = __builtin_amdgcn_mfma_f32_16x16x32_bf16(afrag, bfrag, acc[ni], 0, 0, 0);
      }
    }
    // store agg row into swizzled LDS: s32 = (rr*2+nh)*64 + g*16 + r16
    char* rowp = aggT + lm * 2048;
#pragma unroll
    for (int rr = 0; rr < 4; ++rr)
#pragma unroll
      for (int nh = 0; nh < 2; ++nh) {
        const uint_t v =
            (uint_t)f2bf(acc[nh * 2][rr]) | ((uint_t)f2bf(acc[nh * 2 + 1][rr]) << 16);
        int byte = ((rr * 2 + nh) * 64 + g * 16 + r16) * 4;
        byte ^= (lm & 7) << 4;
        *(uint_t*)(rowp + byte) = v;
      }
    // shortcut: max over neighbors (packed u32, full row per instruction)
    float mx0 = -3.0e38f, mx1 = -3.0e38f;
#pragma unroll
    for (int k = 0; k < KNBR; ++k) {
      const int n = __shfl(idx0, k);
      const uint_t v = *(const uint_t*)(feat16 + (long)n * INDIM + lane * 2);
      mx0 = fmaxf(mx0, __uint_as_float(v << 16));
      mx1 = fmaxf(mx1, __uint_as_float(v & 0xffff0000u));
    }
    ((uint_t*)scmax)[(long)m * 64 + lane] =
        (uint_t)(__float_as_uint(mx0) >> 16) | (__float_as_uint(mx1) & 0xffff0000u);
  }
  __syncthreads();
  // phase 2: x2[16 m x 64 d] = aggT[16 x 1024] @ kpwT2^T ; waves 0..3, 16 d-cols each
  if (wid < 4) {
    f4_t acc2 = zero4();
    const ushort_t* brow = kpwT2 + (long)(wid * 16 + r16) * QD2;
#pragma unroll 8
    for (int kc = 0; kc < 32; ++kc) {
      int byte = (kc * 64 + g * 16) ^ ((r16 & 7) << 4);
      const bf8_t a = *(const bf8_t*)(aggT + r16 * 2048 + byte);
      const bf8_t b = *(const bf8_t*)(brow + kc * 32 + g * 8);
      acc2 = __builtin_amdgcn_mfma_f32_16x16x32_bf16(a, b, acc2, 0, 0, 0);
    }
#pragma unroll
    for (int rr = 0; rr < 4; ++rr) {
      const int m = mbase + g * 4 + rr;
      x2[(long)m * HID + wid * 16 + r16] = f2bf(lrelu(acc2[rr]));
    }
  }
}

// ---------------- conv2 + shortcut conv merged: [M,KD] @ [KD,256] + col-major partials ----
template <int KD>
__device__ __forceinline__ void convT_body(const ushort_t* __restrict__ A,
                                           const ushort_t* __restrict__ Bt,
                                           ushort_t* __restrict__ Oraw,
                                           float* __restrict__ part, int blk) {
  const int tid = threadIdx.x, lane = tid & 63;
  const int wid = tid >> 6;
  const int g = lane >> 4, r16 = lane & 15;
  const int rowbase = blk * 32;
  const int colbase = wid * 64;
  f4_t acc[2][4];
#pragma unroll
  for (int mi = 0; mi < 2; ++mi)
#pragma unroll
    for (int ni = 0; ni < 4; ++ni) acc[mi][ni] = zero4();
#pragma unroll
  for (int kc = 0; kc < KD / 32; ++kc) {
    const int k0 = kc * 32 + g * 8;
    bf8_t a[2], b[4];
#pragma unroll
    for (int mi = 0; mi < 2; ++mi) {
      int row = rowbase + mi * 16 + r16;
      if (row >= MSUB) row = 0;
      a[mi] = *(const bf8_t*)(A + (long)row * KD + k0);
    }
#pragma unroll
    for (int ni = 0; ni < 4; ++ni)
      b[ni] = *(const bf8_t*)(Bt + (long)(colbase + r16 + ni * 16) * KD + k0);
#pragma unroll
    for (int mi = 0; mi < 2; ++mi)
#pragma unroll
      for (int ni = 0; ni < 4; ++ni)
        acc[mi][ni] = __builtin_amdgcn_mfma_f32_16x16x32_bf16(a[mi], b[ni], acc[mi][ni], 0, 0, 0);
  }
  __shared__ float red[2][256];
  red[0][tid] = 0.f;
  red[1][tid] = 0.f;
  __syncthreads();
  float cs[4] = {0.f, 0.f, 0.f, 0.f}, cq[4] = {0.f, 0.f, 0.f, 0.f};
#pragma unroll
  for (int mi = 0; mi < 2; ++mi)
#pragma unroll
    for (int rr = 0; rr < 4; ++rr) {
      const int row = rowbase + mi * 16 + g * 4 + rr;
      if (row < MSUB) {
#pragma unroll
        for (int ni = 0; ni < 4; ++ni) {
          const float v = acc[mi][ni][rr];
          cs[ni] += v;
          cq[ni] += v * v;
          Oraw[(long)row * OUTDIM + colbase + r16 + ni * 16] = f2bf(v);
        }
      }
    }
#pragma unroll
  for (int ni = 0; ni < 4; ++ni) {
    atomicAdd(&red[0][colbase + r16 + ni * 16], cs[ni]);
    atomicAdd(&red[1][colbase + r16 + ni * 16], cq[ni]);
  }
  __syncthreads();
  part[(long)tid * NBT + blk] = red[0][tid];          // column-major
  part[(long)(256 + tid) * NBT + blk] = red[1][tid];
}

__global__ __launch_bounds__(256) void convT_merged_kernel(
    const ushort_t* __restrict__ x2, const ushort_t* __restrict__ W2t,
    const ushort_t* __restrict__ scmax, const ushort_t* __restrict__ Wst,
    ushort_t* __restrict__ x3, ushort_t* __restrict__ scraw,
    float* __restrict__ part2, float* __restrict__ part3) {
  const int b = blockIdx.x;
  if (b < NBT)
    convT_body<HID>(x2, W2t, x3, part2, b);
  else
    convT_body<INDIM>(scmax, Wst, scraw, part3, b - NBT);
}

// ---------------- reduce convT partials + BN2/BN3 affines (512 blocks) ----------------
__global__ __launch_bounds__(256) void reduce23fin_kernel(const float* __restrict__ part2,
                                                          const float* __restrict__ part3,
                                                          const float* __restrict__ g2,
                                                          const float* __restrict__ be2,
                                                          const float* __restrict__ gs,
                                                          const float* __restrict__ bes,
                                                          float* __restrict__ st) {
  const int blk = blockIdx.x, tid = threadIdx.x;
  const int sc = blk >> 8, c = blk & 255;
  const float* part = sc ? part3 : part2;
  const int slot = (tid < 128) ? c : (256 + c);
  const float* src = part + (long)slot * NBT;
  float acc = 0.f;
  for (int i = tid & 127; i < NBT; i += 128) acc += src[i];
  __shared__ float sm[256];
  sm[tid] = acc;
  __syncthreads();
  for (int s = 64; s > 0; s >>= 1) {
    if ((tid & 127) < s) sm[tid] += sm[tid + s];
    __syncthreads();
  }
  if (tid == 0) {
    const float mu = sm[0] / (float)MSUB;
    const float var = sm[128] / (float)MSUB - mu * mu;
    const float a = (sc ? gs : g2)[c] * rsqrtf(var + 1e-5f);
    const int off = sc ? 640 : 128;
    st[off + c] = a;
    st[off + 256 + c] = (sc ? bes : be2)[c] - mu * a;
  }
}

// ---------------- final: BN2/BN3 + lrelu + add + lrelu ----------------
__global__ __launch_bounds__(256) void final_kernel(const ushort_t* __restrict__ x3,
                                                    const ushort_t* __restrict__ sc,
                                                    const float* __restrict__ st,
                                                    float* __restrict__ out) {
  const int i = blockIdx.x * 256 + threadIdx.x;  // 4 elems per thread
  const int c0 = (i * 4) & 255;
  const uint2 xv = ((const uint2*)x3)[i];
  const uint2 sv = ((const uint2*)sc)[i];
  float xs[4] = {bf2f((ushort_t)(xv.x & 0xffffu)), bf2f((ushort_t)(xv.x >> 16)),
                 bf2f((ushort_t)(xv.y & 0xffffu)), bf2f((ushort_t)(xv.y >> 16))};
  float ss[4] = {bf2f((ushort_t)(sv.x & 0xffffu)), bf2f((ushort_t)(sv.x >> 16)),
                 bf2f((ushort_t)(sv.y & 0xffffu)), bf2f((ushort_t)(sv.y >> 16))};
  float r[4];
#pragma unroll
  for (int j = 0; j < 4; ++j) {
    const int c = c0 + j;
    const float v = lrelu(st[128 + c] * xs[j] + st[384 + c]);
    const float u = lrelu(st[640 + c] * ss[j] + st[896 + c]);
    r[j] = lrelu(v + u);
  }
  ((float4*)out)[i] = make_float4(r[0], r[1], r[2], r[3]);
}

extern "C" void kernel_launch(void* const* d_in, const int* in_sizes, int n_in,
                              void* d_out, int out_size, void* d_ws, size_t ws_size,
                              hipStream_t stream) {
  (void)in_sizes; (void)n_in; (void)out_size;
  const float* points = (const float*)d_in[0];
  const float* subp = (const float*)d_in[1];
  const float* feat = (const float*)d_in[2];
  const int* pools = (const int*)d_in[3];
  const float* kp = (const float*)d_in[4];
  const float* W1 = (const float*)d_in[5];
  const float* g1 = (const float*)d_in[7];
  const float* be1 = (const float*)d_in[8];
  const float* kpw = (const float*)d_in[9];
  const float* W2 = (const float*)d_in[10];
  const float* g2 = (const float*)d_in[12];
  const float* be2 = (const float*)d_in[13];
  const float* Wsm = (const float*)d_in[14];
  const float* gs = (const float*)d_in[16];
  const float* bes = (const float*)d_in[17];
  float* out = (float*)d_out;

  char* w = (char*)d_ws;
  size_t o = 0;
  ushort_t* feat16 = (ushort_t*)(w + o); o += (size_t)NPTS * INDIM * 2;   // 51.2 MB
  ushort_t* x1 = (ushort_t*)(w + o);     o += (size_t)NPTS * HID * 2;     // 25.6 MB
  ushort_t* x2 = (ushort_t*)(w + o);     o += (size_t)MSUB * HID * 2;     // 6.4 MB
  ushort_t* x3 = (ushort_t*)(w + o);     o += (size_t)MSUB * OUTDIM * 2;  // 25.6 MB
  ushort_t* scmax = (ushort_t*)(w + o);  o += (size_t)MSUB * INDIM * 2;   // 12.8 MB
  ushort_t* scraw = (ushort_t*)(w + o);  o += (size_t)MSUB * OUTDIM * 2;  // 25.6 MB
  float* part1 = (float*)(w + o);        o += (size_t)128 * NB1 * 4;      // 0.8 MB
  float* part2 = (float*)(w + o);        o += (size_t)512 * NBT * 4;      // 3.2 MB
  float* part3 = (float*)(w + o);        o += (size_t)512 * NBT * 4;      // 3.2 MB
  ushort_t* W1t = (ushort_t*)(w + o);    o += HID * INDIM * 2;
  ushort_t* W2t = (ushort_t*)(w + o);    o += OUTDIM * HID * 2;
  ushort_t* Wst = (ushort_t*)(w + o);    o += OUTDIM * INDIM * 2;
  ushort_t* kpwT2 = (ushort_t*)(w + o);  o += HID * QD2 * 2;
  float* st = (float*)(w + o);           o += 1152 * 4;
  if (ws_size < o) return;  // fail cleanly

  prep_w_kernel<<<64, 256, 0, stream>>>(W1, W2, Wsm, kpw, W1t, W2t, Wst, kpwT2);
  conv1_kernel<<<NB1, 256, 0, stream>>>(feat, W1t, feat16, x1, part1);
  reduce1fin_kernel<<<64, 256, 0, stream>>>(part1, g1, be1, st);
  gkp_kernel<<<MSUB / 16, 512, 0, stream>>>(points, subp, pools, kp, x1, feat16, st,
                                            kpwT2, x2, scmax);
  convT_merged_kernel<<<2 * NBT, 256, 0, stream>>>(x2, W2t, scmax, Wst, x3, scraw,
                                                   part2, part3);
  reduce23fin_kernel<<<512, 256, 0, stream>>>(part2, part3, g2, be2, gs, bes, st);
  final_kernel<<<MSUB * OUTDIM / 1024, 256, 0, stream>>>(x3, scraw, st, out);
}

// Round 13
// 259.353 us; speedup vs baseline: 1.7564x; 1.1272x over previous
//
#include <hip/hip_runtime.h>

typedef unsigned short ushort_t;
typedef unsigned int uint_t;
typedef __attribute__((ext_vector_type(8))) short bf8_t;   // 8 x bf16 (4 VGPRs)
typedef __attribute__((ext_vector_type(4))) float f4_t;    // MFMA acc
typedef __attribute__((ext_vector_type(4))) unsigned int u4_t;

#define NPTS 200000
#define MSUB 50000
#define KNBR 32
#define PK 15
#define INDIM 128
#define OUTDIM 256
#define HID 64
#define QD2 1024  // padded PK*HID (p=15 row zero)
#define NB1 1563  // conv1 blocks = ceil(NPTS/128)
#define NBC 782   // convT blocks = ceil(MSUB/64)

__device__ __forceinline__ ushort_t f2bf(float f) {
  uint_t u = __float_as_uint(f);
  u = (u + 0x7fffu + ((u >> 16) & 1u)) >> 16;  // RNE
  return (ushort_t)u;
}
__device__ __forceinline__ float bf2f(ushort_t h) {
  return __uint_as_float(((uint_t)h) << 16);
}
__device__ __forceinline__ float lrelu(float x) { return fmaxf(x, 0.1f * x); }
__device__ __forceinline__ f4_t zero4() { f4_t z = {0.f, 0.f, 0.f, 0.f}; return z; }

// ---------------- prep: weight transposes to bf16 ----------------
__global__ void prep_w_kernel(const float* __restrict__ W1, const float* __restrict__ W2,
                              const float* __restrict__ Ws, const float* __restrict__ kpw,
                              ushort_t* __restrict__ W1t, ushort_t* __restrict__ W2t,
                              ushort_t* __restrict__ Wst, ushort_t* __restrict__ kpwT2) {
  const int base = blockIdx.x * blockDim.x + threadIdx.x;
  const int stride = gridDim.x * blockDim.x;
  for (int t = base; t < HID * INDIM; t += stride) {      // W1t[c][k] = W1[k][c]
    int c = t & 63, k = t >> 6;
    W1t[c * INDIM + k] = f2bf(W1[k * HID + c]);
  }
  for (int t = base; t < OUTDIM * HID; t += stride) {     // W2t[c][k]
    int c = t & 255, k = t >> 8;
    W2t[c * HID + k] = f2bf(W2[k * OUTDIM + c]);
  }
  for (int t = base; t < OUTDIM * INDIM; t += stride) {   // Wst[c][k]
    int c = t & 255, k = t >> 8;
    Wst[c * INDIM + k] = f2bf(Ws[k * OUTDIM + c]);
  }
  // kpwT2[d][s]: s-permuted to match gather's agg D-layout pack.
  // s = ((rr*2+nh)*64 + g*16 + r16)*2 + nl ; p = g*4+rr ; c = r16+(nh*2+nl)*16
  for (int t = base; t < HID * QD2; t += stride) {
    int d = t >> 10, s = t & 1023;
    int nl = s & 1, r16v = (s >> 1) & 15, gv = (s >> 5) & 3, nh = (s >> 7) & 1, rr = (s >> 8) & 3;
    int p = gv * 4 + rr, c = r16v + (nh * 2 + nl) * 16;
    float v = (p < PK) ? kpw[((long)p * HID + c) * HID + d] : 0.f;
    kpwT2[d * QD2 + s] = f2bf(v);
  }
}

// ---------------- conv1: feat f32 -> feat16 + x1raw [N,64] + col-major partials ----------
__global__ __launch_bounds__(256) void conv1_kernel(const float* __restrict__ feat,
                                                    const ushort_t* __restrict__ W1t,
                                                    ushort_t* __restrict__ feat16,
                                                    ushort_t* __restrict__ x1,
                                                    float* __restrict__ part1) {
  const int tid = threadIdx.x, wid = tid >> 6, lane = tid & 63;
  const int g = lane >> 4, r16 = lane & 15;
  const int rowbase = blockIdx.x * 128 + wid * 32;
  f4_t acc[2][4];
#pragma unroll
  for (int mi = 0; mi < 2; ++mi)
#pragma unroll
    for (int ni = 0; ni < 4; ++ni) acc[mi][ni] = zero4();
#pragma unroll
  for (int kc = 0; kc < 4; ++kc) {
    const int k0 = kc * 32 + g * 8;
    bf8_t a[2], b[4];
#pragma unroll
    for (int mi = 0; mi < 2; ++mi) {
      const int row = rowbase + mi * 16 + r16;
      const int rowc = (row < NPTS) ? row : 0;
      const float4 f0 = *(const float4*)(feat + (long)rowc * INDIM + k0);
      const float4 f1 = *(const float4*)(feat + (long)rowc * INDIM + k0 + 4);
      a[mi][0] = (short)f2bf(f0.x); a[mi][1] = (short)f2bf(f0.y);
      a[mi][2] = (short)f2bf(f0.z); a[mi][3] = (short)f2bf(f0.w);
      a[mi][4] = (short)f2bf(f1.x); a[mi][5] = (short)f2bf(f1.y);
      a[mi][6] = (short)f2bf(f1.z); a[mi][7] = (short)f2bf(f1.w);
      if (row < NPTS) *(bf8_t*)(feat16 + (long)row * INDIM + k0) = a[mi];
    }
#pragma unroll
    for (int ni = 0; ni < 4; ++ni)
      b[ni] = *(const bf8_t*)(W1t + (r16 + ni * 16) * INDIM + k0);
#pragma unroll
    for (int mi = 0; mi < 2; ++mi)
#pragma unroll
      for (int ni = 0; ni < 4; ++ni)
        acc[mi][ni] = __builtin_amdgcn_mfma_f32_16x16x32_bf16(a[mi], b[ni], acc[mi][ni], 0, 0, 0);
  }
  __shared__ float red[2][64];
  if (tid < 64) { red[0][tid] = 0.f; red[1][tid] = 0.f; }
  __syncthreads();
  float cs[4] = {0.f, 0.f, 0.f, 0.f}, cq[4] = {0.f, 0.f, 0.f, 0.f};
#pragma unroll
  for (int mi = 0; mi < 2; ++mi)
#pragma unroll
    for (int rr = 0; rr < 4; ++rr) {
      const int row = rowbase + mi * 16 + g * 4 + rr;
      if (row < NPTS) {
#pragma unroll
        for (int ni = 0; ni < 4; ++ni) {
          const float v = acc[mi][ni][rr];
          cs[ni] += v;
          cq[ni] += v * v;
          x1[(long)row * HID + r16 + ni * 16] = f2bf(v);
        }
      }
    }
#pragma unroll
  for (int ni = 0; ni < 4; ++ni) {
    atomicAdd(&red[0][r16 + ni * 16], cs[ni]);
    atomicAdd(&red[1][r16 + ni * 16], cq[ni]);
  }
  __syncthreads();
  if (tid < 128) {
    const float v = (tid < 64) ? red[0][tid] : red[1][tid - 64];
    part1[(long)tid * NB1 + blockIdx.x] = v;  // column-major partials
  }
}

// ---------------- reduce conv1 partials + BN1 affine (64 blocks) ----------------
__global__ __launch_bounds__(256) void reduce1fin_kernel(const float* __restrict__ part1,
                                                         const float* __restrict__ g1,
                                                         const float* __restrict__ be1,
                                                         float* __restrict__ st) {
  const int c = blockIdx.x, tid = threadIdx.x;
  const int slot = (tid < 128) ? c : (64 + c);
  const float* src = part1 + (long)slot * NB1;
  float acc = 0.f;
  for (int i = tid & 127; i < NB1; i += 128) acc += src[i];
  __shared__ float sm[256];
  sm[tid] = acc;
  __syncthreads();
  for (int s = 64; s > 0; s >>= 1) {
    if ((tid & 127) < s) sm[tid] += sm[tid + s];
    __syncthreads();
  }
  if (tid == 0) {
    const float mu = sm[0] / (float)NPTS;
    const float var = sm[128] / (float)NPTS - mu * mu;
    const float a = g1[c] * rsqrtf(var + 1e-5f);
    st[c] = a;
    st[64 + c] = be1[c] - mu * a;
  }
}

// ---------------- gkp: gather + per-m agg MFMA + fused [16x1024]@[1024x64] GEMM ----------
// R9 verbatim (measured 137.5 us): 512 threads = 8 waves, 16 m per block (2 per wave),
// ft2 = [8][32][36] u32 (36 KB) + aggT 32 KB = 69.6 KB -> 2 blocks/CU.
__global__ __launch_bounds__(512, 4) void gkp_kernel(
    const float* __restrict__ points, const float* __restrict__ subp,
    const int* __restrict__ pools, const float* __restrict__ kp,
    const ushort_t* __restrict__ x1, const ushort_t* __restrict__ feat16,
    const float* __restrict__ st, const ushort_t* __restrict__ kpwT2,
    ushort_t* __restrict__ x2, ushort_t* __restrict__ scmax) {
  const int tid = threadIdx.x, wid = tid >> 6, lane = tid & 63;
  const int g = lane >> 4, r16 = lane & 15, l31 = lane & 31, hi = lane >> 5;
  const int mbase = blockIdx.x * 16;
  __shared__ __align__(16) char aggT[16 * 2048];   // 16 rows x 1024 bf16, XOR-swizzled (32 KB)
  __shared__ __align__(16) uint_t ft2[8][32][36];  // per-wave gathered h, u32 = 2 bf16 (36 KB)
  // per-lane BN1 affine for c = r16 + ni*16
  float A4[4], S4[4];
#pragma unroll
  for (int ni = 0; ni < 4; ++ni) {
    A4[ni] = st[r16 + ni * 16];
    S4[ni] = st[64 + r16 + ni * 16];
  }
  const int p = r16;
  const int pc = (p < PK) ? p : 0;
  const float kx = kp[pc * 3 + 0], ky = kp[pc * 3 + 1], kz = kp[pc * 3 + 2];

#pragma unroll
  for (int mm = 0; mm < 2; ++mm) {
    const int lm = wid * 2 + mm;
    const int m = mbase + lm;
    // neighbor idx + point coords in lanes 0..31 (broadcast via shfl)
    const int idx0 = pools[m * KNBR + l31];
    float px = 0.f, py = 0.f, pz = 0.f;
    if (lane < 32) {
      px = points[idx0 * 3 + 0];
      py = points[idx0 * 3 + 1];
      pz = points[idx0 * 3 + 2];
    }
    // gather x1 rows -> ft2[c2][k]
#pragma unroll
    for (int i = 0; i < 16; ++i) {
      const int k = 2 * i + hi;
      const int n = __shfl(idx0, k);
      ft2[wid][l31][k] = *(const uint_t*)(x1 + (long)n * HID + l31 * 2);
    }
    const float sx = subp[m * 3 + 0], sy = subp[m * 3 + 1], sz = subp[m * 3 + 2];
    // A fragment: w^T[p][k], computed in-lane
    const float kxx = kx + sx, kyy = ky + sy, kzz = kz + sz;
    bf8_t afrag;
#pragma unroll
    for (int j = 0; j < 8; ++j) {
      const int k = g * 8 + j;
      const float dx = __shfl(px, k) - kxx;
      const float dy = __shfl(py, k) - kyy;
      const float dz = __shfl(pz, k) - kzz;
      const float dist = sqrtf(dx * dx + dy * dy + dz * dz);
      float w = fmaxf(0.f, 1.f - dist * 20.f);
      if (p >= PK) w = 0.f;
      afrag[j] = (short)f2bf(w);
    }
    // B fragments: extract + BN1 + lrelu + pack
    f4_t acc[4];
#pragma unroll
    for (int ni = 0; ni < 4; ++ni) acc[ni] = zero4();
#pragma unroll
    for (int ni = 0; ni < 4; ++ni) {
      const int c = r16 + ni * 16;
      const int c2 = c >> 1;
      const int sh = (c & 1) * 16;
      const float A = A4[ni], S = S4[ni];
      const uint_t* src = &ft2[wid][c2][g * 8];
      const u4_t v0 = *(const u4_t*)src;
      const u4_t v1 = *(const u4_t*)(src + 4);
      bf8_t bfrag;
#pragma unroll
      for (int j = 0; j < 4; ++j) {
        const float xa = __uint_as_float(((v0[j] >> sh) & 0xffffu) << 16);
        bfrag[j] = (short)f2bf(lrelu(A * xa + S));
        const float xb = __uint_as_float(((v1[j] >> sh) & 0xffffu) << 16);
        bfrag[4 + j] = (short)f2bf(lrelu(A * xb + S));
      }
      acc[ni] = __builtin_amdgcn_mfma_f32_16x16x32_bf16(afrag, bfrag, acc[ni], 0, 0, 0);
    }
    // store agg row into swizzled LDS: s32 = (rr*2+nh)*64 + g*16 + r16
    char* rowp = aggT + lm * 2048;
#pragma unroll
    for (int rr = 0; rr < 4; ++rr)
#pragma unroll
      for (int nh = 0; nh < 2; ++nh) {
        const uint_t v =
            (uint_t)f2bf(acc[nh * 2][rr]) | ((uint_t)f2bf(acc[nh * 2 + 1][rr]) << 16);
        int byte = ((rr * 2 + nh) * 64 + g * 16 + r16) * 4;
        byte ^= (lm & 7) << 4;
        *(uint_t*)(rowp + byte) = v;
      }
    // shortcut: max over neighbors (packed u32, full row per instruction)
    float mx0 = -3.0e38f, mx1 = -3.0e38f;
#pragma unroll
    for (int k = 0; k < KNBR; ++k) {
      const int n = __shfl(idx0, k);
      const uint_t v = *(const uint_t*)(feat16 + (long)n * INDIM + lane * 2);
      mx0 = fmaxf(mx0, __uint_as_float(v << 16));
      mx1 = fmaxf(mx1, __uint_as_float(v & 0xffff0000u));
    }
    ((uint_t*)scmax)[(long)m * 64 + lane] =
        (uint_t)(__float_as_uint(mx0) >> 16) | (__float_as_uint(mx1) & 0xffff0000u);
  }
  __syncthreads();
  // phase 2: x2[16 m x 64 d] = aggT[16 x 1024] @ kpwT2^T ; waves 0..3, 16 d-cols each
  if (wid < 4) {
    f4_t acc2 = zero4();
    const ushort_t* brow = kpwT2 + (long)(wid * 16 + r16) * QD2;
#pragma unroll 8
    for (int kc = 0; kc < 32; ++kc) {
      int byte = (kc * 64 + g * 16) ^ ((r16 & 7) << 4);
      const bf8_t a = *(const bf8_t*)(aggT + r16 * 2048 + byte);
      const bf8_t b = *(const bf8_t*)(brow + kc * 32 + g * 8);
      acc2 = __builtin_amdgcn_mfma_f32_16x16x32_bf16(a, b, acc2, 0, 0, 0);
    }
#pragma unroll
    for (int rr = 0; rr < 4; ++rr) {
      const int m = mbase + g * 4 + rr;
      x2[(long)m * HID + wid * 16 + r16] = f2bf(lrelu(acc2[rr]));
    }
  }
}

// ---------------- conv2 + shortcut conv merged: 64-row tiles + col-major partials ----------
template <int KD>
__device__ __forceinline__ void convT_body(const ushort_t* __restrict__ A,
                                           const ushort_t* __restrict__ Bt,
                                           ushort_t* __restrict__ Oraw,
                                           float* __restrict__ part, int blk) {
  const int tid = threadIdx.x, lane = tid & 63;
  const int wid = tid >> 6;
  const int g = lane >> 4, r16 = lane & 15;
  const int rowbase = blk * 64;
  const int colbase = wid * 64;
  f4_t acc[4][4];
#pragma unroll
  for (int mi = 0; mi < 4; ++mi)
#pragma unroll
    for (int ni = 0; ni < 4; ++ni) acc[mi][ni] = zero4();
#pragma unroll
  for (int kc = 0; kc < KD / 32; ++kc) {
    const int k0 = kc * 32 + g * 8;
    bf8_t a[4], b[4];
#pragma unroll
    for (int mi = 0; mi < 4; ++mi) {
      int row = rowbase + mi * 16 + r16;
      if (row >= MSUB) row = 0;
      a[mi] = *(const bf8_t*)(A + (long)row * KD + k0);
    }
#pragma unroll
    for (int ni = 0; ni < 4; ++ni)
      b[ni] = *(const bf8_t*)(Bt + (long)(colbase + r16 + ni * 16) * KD + k0);
#pragma unroll
    for (int mi = 0; mi < 4; ++mi)
#pragma unroll
      for (int ni = 0; ni < 4; ++ni)
        acc[mi][ni] = __builtin_amdgcn_mfma_f32_16x16x32_bf16(a[mi], b[ni], acc[mi][ni], 0, 0, 0);
  }
  __shared__ float red[2][256];
  red[0][tid] = 0.f;
  red[1][tid] = 0.f;
  __syncthreads();
  float cs[4] = {0.f, 0.f, 0.f, 0.f}, cq[4] = {0.f, 0.f, 0.f, 0.f};
#pragma unroll
  for (int mi = 0; mi < 4; ++mi)
#pragma unroll
    for (int rr = 0; rr < 4; ++rr) {
      const int row = rowbase + mi * 16 + g * 4 + rr;
      if (row < MSUB) {
#pragma unroll
        for (int ni = 0; ni < 4; ++ni) {
          const float v = acc[mi][ni][rr];
          cs[ni] += v;
          cq[ni] += v * v;
          Oraw[(long)row * OUTDIM + colbase + r16 + ni * 16] = f2bf(v);
        }
      }
    }
#pragma unroll
  for (int ni = 0; ni < 4; ++ni) {
    atomicAdd(&red[0][colbase + r16 + ni * 16], cs[ni]);
    atomicAdd(&red[1][colbase + r16 + ni * 16], cq[ni]);
  }
  __syncthreads();
  part[(long)tid * NBC + blk] = red[0][tid];          // column-major
  part[(long)(256 + tid) * NBC + blk] = red[1][tid];
}

__global__ __launch_bounds__(256) void convT_merged_kernel(
    const ushort_t* __restrict__ x2, const ushort_t* __restrict__ W2t,
    const ushort_t* __restrict__ scmax, const ushort_t* __restrict__ Wst,
    ushort_t* __restrict__ x3, ushort_t* __restrict__ scraw,
    float* __restrict__ part2, float* __restrict__ part3) {
  const int b = blockIdx.x;
  if (b < NBC)
    convT_body<HID>(x2, W2t, x3, part2, b);
  else
    convT_body<INDIM>(scmax, Wst, scraw, part3, b - NBC);
}

// ---------------- reduce convT partials + BN2/BN3 affines (512 blocks) ----------------
__global__ __launch_bounds__(256) void reduce23fin_kernel(const float* __restrict__ part2,
                                                          const float* __restrict__ part3,
                                                          const float* __restrict__ g2,
                                                          const float* __restrict__ be2,
                                                          const float* __restrict__ gs,
                                                          const float* __restrict__ bes,
                                                          float* __restrict__ st) {
  const int blk = blockIdx.x, tid = threadIdx.x;
  const int sc = blk >> 8, c = blk & 255;
  const float* part = sc ? part3 : part2;
  const int slot = (tid < 128) ? c : (256 + c);
  const float* src = part + (long)slot * NBC;
  float acc = 0.f;
  for (int i = tid & 127; i < NBC; i += 128) acc += src[i];
  __shared__ float sm[256];
  sm[tid] = acc;
  __syncthreads();
  for (int s = 64; s > 0; s >>= 1) {
    if ((tid & 127) < s) sm[tid] += sm[tid + s];
    __syncthreads();
  }
  if (tid == 0) {
    const float mu = sm[0] / (float)MSUB;
    const float var = sm[128] / (float)MSUB - mu * mu;
    const float a = (sc ? gs : g2)[c] * rsqrtf(var + 1e-5f);
    const int off = sc ? 640 : 128;
    st[off + c] = a;
    st[off + 256 + c] = (sc ? bes : be2)[c] - mu * a;
  }
}

// ---------------- final: BN2/BN3 + lrelu + add + lrelu ----------------
__global__ __launch_bounds__(256) void final_kernel(const ushort_t* __restrict__ x3,
                                                    const ushort_t* __restrict__ sc,
                                                    const float* __restrict__ st,
                                                    float* __restrict__ out) {
  const int i = blockIdx.x * 256 + threadIdx.x;  // 4 elems per thread
  const int c0 = (i * 4) & 255;
  const uint2 xv = ((const uint2*)x3)[i];
  const uint2 sv = ((const uint2*)sc)[i];
  float xs[4] = {bf2f((ushort_t)(xv.x & 0xffffu)), bf2f((ushort_t)(xv.x >> 16)),
                 bf2f((ushort_t)(xv.y & 0xffffu)), bf2f((ushort_t)(xv.y >> 16))};
  float ss[4] = {bf2f((ushort_t)(sv.x & 0xffffu)), bf2f((ushort_t)(sv.x >> 16)),
                 bf2f((ushort_t)(sv.y & 0xffffu)), bf2f((ushort_t)(sv.y >> 16))};
  float r[4];
#pragma unroll
  for (int j = 0; j < 4; ++j) {
    const int c = c0 + j;
    const float v = lrelu(st[128 + c] * xs[j] + st[384 + c]);
    const float u = lrelu(st[640 + c] * ss[j] + st[896 + c]);
    r[j] = lrelu(v + u);
  }
  ((float4*)out)[i] = make_float4(r[0], r[1], r[2], r[3]);
}

extern "C" void kernel_launch(void* const* d_in, const int* in_sizes, int n_in,
                              void* d_out, int out_size, void* d_ws, size_t ws_size,
                              hipStream_t stream) {
  (void)in_sizes; (void)n_in; (void)out_size;
  const float* points = (const float*)d_in[0];
  const float* subp = (const float*)d_in[1];
  const float* feat = (const float*)d_in[2];
  const int* pools = (const int*)d_in[3];
  const float* kp = (const float*)d_in[4];
  const float* W1 = (const float*)d_in[5];
  const float* g1 = (const float*)d_in[7];
  const float* be1 = (const float*)d_in[8];
  const float* kpw = (const float*)d_in[9];
  const float* W2 = (const float*)d_in[10];
  const float* g2 = (const float*)d_in[12];
  const float* be2 = (const float*)d_in[13];
  const float* Wsm = (const float*)d_in[14];
  const float* gs = (const float*)d_in[16];
  const float* bes = (const float*)d_in[17];
  float* out = (float*)d_out;

  char* w = (char*)d_ws;
  size_t o = 0;
  ushort_t* feat16 = (ushort_t*)(w + o); o += (size_t)NPTS * INDIM * 2;   // 51.2 MB
  ushort_t* x1 = (ushort_t*)(w + o);     o += (size_t)NPTS * HID * 2;     // 25.6 MB
  ushort_t* x2 = (ushort_t*)(w + o);     o += (size_t)MSUB * HID * 2;     // 6.4 MB
  ushort_t* x3 = (ushort_t*)(w + o);     o += (size_t)MSUB * OUTDIM * 2;  // 25.6 MB
  ushort_t* scmax = (ushort_t*)(w + o);  o += (size_t)MSUB * INDIM * 2;   // 12.8 MB
  ushort_t* scraw = (ushort_t*)(w + o);  o += (size_t)MSUB * OUTDIM * 2;  // 25.6 MB
  float* part1 = (float*)(w + o);        o += (size_t)128 * NB1 * 4;      // 0.8 MB
  float* part2 = (float*)(w + o);        o += (size_t)512 * NBC * 4;      // 1.6 MB
  float* part3 = (float*)(w + o);        o += (size_t)512 * NBC * 4;      // 1.6 MB
  ushort_t* W1t = (ushort_t*)(w + o);    o += HID * INDIM * 2;
  ushort_t* W2t = (ushort_t*)(w + o);    o += OUTDIM * HID * 2;
  ushort_t* Wst = (ushort_t*)(w + o);    o += OUTDIM * INDIM * 2;
  ushort_t* kpwT2 = (ushort_t*)(w + o);  o += HID * QD2 * 2;
  float* st = (float*)(w + o);           o += 1152 * 4;
  if (ws_size < o) return;  // fail cleanly

  prep_w_kernel<<<64, 256, 0, stream>>>(W1, W2, Wsm, kpw, W1t, W2t, Wst, kpwT2);
  conv1_kernel<<<NB1, 256, 0, stream>>>(feat, W1t, feat16, x1, part1);
  reduce1fin_kernel<<<64, 256, 0, stream>>>(part1, g1, be1, st);
  gkp_kernel<<<MSUB / 16, 512, 0, stream>>>(points, subp, pools, kp, x1, feat16, st,
                                            kpwT2, x2, scmax);
  convT_merged_kernel<<<2 * NBC, 256, 0, stream>>>(x2, W2t, scmax, Wst, x3, scraw,
                                                   part2, part3);
  reduce23fin_kernel<<<512, 256, 0, stream>>>(part2, part3, g2, be2, gs, bes, st);
  final_kernel<<<MSUB * OUTDIM / 1024, 256, 0, stream>>>(x3, scraw, st, out);
}